// Round 1
// baseline (4507.596 us; speedup 1.0000x reference)
//
#include <hip/hip_runtime.h>
#include <cstdint>
#include <cmath>

#define DD 2048
#define TT 2048
#define HH 16
#define HDD 128
#define MROWS 4096  // B*T

typedef __attribute__((ext_vector_type(8))) short s16x8;
typedef __attribute__((ext_vector_type(4))) float f32x4;

typedef const __attribute__((address_space(1))) void gvoid;
typedef __attribute__((address_space(3))) void lvoid;

__device__ __forceinline__ void async_cp16(const void* g, void* l) {
    __builtin_amdgcn_global_load_lds((gvoid*)g, (lvoid*)l, 16, 0, 0);
}

__device__ __forceinline__ unsigned short f2bf(float f) {
    unsigned int u = __float_as_uint(f);
    u += 0x7fffu + ((u >> 16) & 1u);
    return (unsigned short)(u >> 16);
}

__device__ __forceinline__ void store4bf(unsigned short* p, float a, float b, float c, float d) {
    union { unsigned short u[4]; uint2 v; } x;
    x.u[0] = f2bf(a); x.u[1] = f2bf(b); x.u[2] = f2bf(c); x.u[3] = f2bf(d);
    *(uint2*)p = x.v;
}

// ---------------- fp32 -> bf16 convert ----------------
__global__ __launch_bounds__(256) void cvt_bf16(const float* __restrict__ src,
                                                unsigned short* __restrict__ dst, int n4) {
    int i = blockIdx.x * 256 + threadIdx.x;
    if (i < n4) {
        float4 v = ((const float4*)src)[i];
        store4bf(dst + (size_t)i * 4, v.x, v.y, v.z, v.w);
    }
}

// ---------------- LayerNorm (fp32 in, bf16 out) ----------------
__global__ __launch_bounds__(256) void ln_bf16(const float* __restrict__ x,
                                               const float* __restrict__ gg,
                                               const float* __restrict__ bb,
                                               unsigned short* __restrict__ out) {
    __shared__ float red[8];
    const int row = blockIdx.x, t = threadIdx.x;
    const float* xr = x + (size_t)row * DD;
    float4 a = ((const float4*)xr)[t];
    float4 c = ((const float4*)xr)[t + 256];
    float s = a.x + a.y + a.z + a.w + c.x + c.y + c.z + c.w;
    float q = a.x*a.x + a.y*a.y + a.z*a.z + a.w*a.w + c.x*c.x + c.y*c.y + c.z*c.z + c.w*c.w;
    for (int m = 1; m < 64; m <<= 1) { s += __shfl_xor(s, m); q += __shfl_xor(q, m); }
    if ((t & 63) == 0) { red[t >> 6] = s; red[4 + (t >> 6)] = q; }
    __syncthreads();
    s = red[0] + red[1] + red[2] + red[3];
    q = red[4] + red[5] + red[6] + red[7];
    float mean = s * (1.f / DD);
    float var = q * (1.f / DD) - mean * mean;
    float rstd = rsqrtf(var + 1e-5f);
    float4 g1 = ((const float4*)gg)[t], b1 = ((const float4*)bb)[t];
    float4 g2 = ((const float4*)gg)[t + 256], b2 = ((const float4*)bb)[t + 256];
    unsigned short* orow = out + (size_t)row * DD;
    store4bf(orow + 4 * t,
             (a.x - mean) * rstd * g1.x + b1.x, (a.y - mean) * rstd * g1.y + b1.y,
             (a.z - mean) * rstd * g1.z + b1.z, (a.w - mean) * rstd * g1.w + b1.w);
    store4bf(orow + 1024 + 4 * t,
             (c.x - mean) * rstd * g2.x + b2.x, (c.y - mean) * rstd * g2.y + b2.y,
             (c.z - mean) * rstd * g2.z + b2.z, (c.w - mean) * rstd * g2.w + b2.w);
}

// ---------------- dual gated GEMM ----------------
// out[m,n] = epi( (A·W^T + b)[m,n] * sigmoid((A·Wg^T + bg)[m,n]) )
// A: MxK bf16 row-major; W,Wg: NxK bf16 row-major. 128x128 tile, BK=32.
// EPI: 0 = bf16 store (q,k); 1 = bf16 transposed-V store; 2 = fp32 resid add; 3 = gelu->bf16
template <int EPI>
__global__ __launch_bounds__(256, 2) void gemm_gated(
        const unsigned short* __restrict__ A, const unsigned short* __restrict__ W,
        const unsigned short* __restrict__ Wg, const float* __restrict__ bias,
        const float* __restrict__ biasg, const float* __restrict__ resid,
        void* __restrict__ outp, int M, int N, int K) {
    __shared__ unsigned short lds_[12288];  // A[0,4096) B[4096,8192) Bg[8192,12288)
    const int t = threadIdx.x, lane = t & 63, wv = t >> 6;
    const int m0 = blockIdx.y * 128, n0 = blockIdx.x * 128;

    const int srow = wv * 32 + (lane >> 2);
    const int scol = (lane & 3) * 8;
    const unsigned short* gA = A + (size_t)(m0 + srow) * K + scol;
    const unsigned short* gB = W + (size_t)(n0 + srow) * K + scol;
    const unsigned short* gBg = Wg + (size_t)(n0 + srow) * K + scol;
    unsigned short* lA = lds_ + wv * 1024 + lane * 8;
    unsigned short* lB = lA + 4096;
    unsigned short* lBg = lA + 8192;

    const int mw = (wv >> 1) * 64, nw = (wv & 1) * 64;
    const int fr = lane & 15, fg = lane >> 4, fk = fg * 8;

    f32x4 zero4 = {0.f, 0.f, 0.f, 0.f};
    f32x4 acc[4][4], accg[4][4];
    for (int i = 0; i < 4; i++)
        for (int j = 0; j < 4; j++) { acc[i][j] = zero4; accg[i][j] = zero4; }

    for (int k0 = 0; k0 < K; k0 += 32) {
        async_cp16(gA + k0, lA);
        async_cp16(gA + k0 + (size_t)16 * K, lA + 512);
        async_cp16(gB + k0, lB);
        async_cp16(gB + k0 + (size_t)16 * K, lB + 512);
        async_cp16(gBg + k0, lBg);
        async_cp16(gBg + k0 + (size_t)16 * K, lBg + 512);
        __syncthreads();  // drains vmcnt(0) before barrier
        s16x8 af[4], bf_[4], bg_[4];
        for (int i = 0; i < 4; i++)
            af[i] = *(const s16x8*)(lds_ + (mw + i * 16 + fr) * 32 + fk);
        for (int j = 0; j < 4; j++) {
            bf_[j] = *(const s16x8*)(lds_ + 4096 + (nw + j * 16 + fr) * 32 + fk);
            bg_[j] = *(const s16x8*)(lds_ + 8192 + (nw + j * 16 + fr) * 32 + fk);
        }
        for (int i = 0; i < 4; i++)
            for (int j = 0; j < 4; j++) {
                acc[i][j] = __builtin_amdgcn_mfma_f32_16x16x32_bf16(af[i], bf_[j], acc[i][j], 0, 0, 0);
                accg[i][j] = __builtin_amdgcn_mfma_f32_16x16x32_bf16(af[i], bg_[j], accg[i][j], 0, 0, 0);
            }
        __syncthreads();
    }

    for (int i = 0; i < 4; i++)
        for (int j = 0; j < 4; j++) {
            const int n = n0 + nw + j * 16 + fr;
            const float bn = bias[n], bgn = biasg[n];
            for (int r = 0; r < 4; r++) {
                const int m = m0 + mw + i * 16 + fg * 4 + r;
                float lin = acc[i][j][r] + bn;
                float gt = accg[i][j][r] + bgn;
                float gv = lin / (1.f + __expf(-gt));
                if constexpr (EPI == 0) {
                    ((unsigned short*)outp)[(size_t)m * N + n] = f2bf(gv);
                } else if constexpr (EPI == 1) {
                    // V transposed: vT[((b*H + h)*HD + hd)*T + t]
                    int bb_ = m >> 11, tt_ = m & 2047;
                    ((unsigned short*)outp)[(((size_t)bb_ * HH + (n >> 7)) * HDD + (n & 127)) * TT + tt_] = f2bf(gv);
                } else if constexpr (EPI == 2) {
                    ((float*)outp)[(size_t)m * N + n] = resid[(size_t)m * N + n] + gv;
                } else {
                    float ge = 0.5f * gv * (1.f + erff(gv * 0.70710678118f));
                    ((unsigned short*)outp)[(size_t)m * N + n] = f2bf(ge);
                }
            }
        }
}

// ---------------- flash attention ----------------
// One wave (64 thr) per (b, h, 16 q-rows). Q,K normal layout [ (b*T+t)*D + h*HD+hd ],
// V transposed [ ((b*H+h)*HD+hd)*T + t ]. Full softmax (no mask).
__global__ __launch_bounds__(64) void attn_flash(const unsigned short* __restrict__ Q,
                                                 const unsigned short* __restrict__ Kb,
                                                 const unsigned short* __restrict__ VT,
                                                 unsigned short* __restrict__ Y) {
    __shared__ unsigned short Pl[16 * 64];
    const int lane = threadIdx.x;
    const int bx = blockIdx.x;
    const int q0 = (bx & 127) * 16;
    const int h = (bx >> 7) & 15;
    const int b = bx >> 11;
    const int fr = lane & 15, fg = lane >> 4;

    s16x8 qf[4];
    const unsigned short* qbase = Q + ((size_t)(b * TT + q0 + fr)) * DD + h * HDD + fg * 8;
    for (int s = 0; s < 4; s++) qf[s] = *(const s16x8*)(qbase + s * 32);

    f32x4 zero4 = {0.f, 0.f, 0.f, 0.f};
    f32x4 o[8];
    for (int jo = 0; jo < 8; jo++) o[jo] = zero4;
    float Mx[4], L[4];
    for (int r = 0; r < 4; r++) { Mx[r] = -1e30f; L[r] = 0.f; }

    const unsigned short* kbase = Kb + (size_t)(b * TT) * DD + h * HDD + fg * 8;
    const unsigned short* vbase = VT + ((size_t)((b * HH + h) * HDD + fr)) * TT + fg * 8;
    const float scale = 0.08838834764831845f;  // 1/sqrt(128)

    for (int tk0 = 0; tk0 < TT; tk0 += 64) {
        f32x4 sac[4];
        for (int j = 0; j < 4; j++) sac[j] = zero4;
        for (int j = 0; j < 4; j++) {
            const unsigned short* kp = kbase + (size_t)(tk0 + j * 16 + fr) * DD;
            for (int s = 0; s < 4; s++) {
                s16x8 kf = *(const s16x8*)(kp + s * 32);
                sac[j] = __builtin_amdgcn_mfma_f32_16x16x32_bf16(qf[s], kf, sac[j], 0, 0, 0);
            }
        }
        float alpha[4];
        for (int j = 0; j < 4; j++)
            for (int r = 0; r < 4; r++) sac[j][r] *= scale;
        for (int r = 0; r < 4; r++) {
            float mx = fmaxf(fmaxf(sac[0][r], sac[1][r]), fmaxf(sac[2][r], sac[3][r]));
            mx = fmaxf(mx, __shfl_xor(mx, 1));
            mx = fmaxf(mx, __shfl_xor(mx, 2));
            mx = fmaxf(mx, __shfl_xor(mx, 4));
            mx = fmaxf(mx, __shfl_xor(mx, 8));
            float mnew = fmaxf(Mx[r], mx);
            alpha[r] = __expf(Mx[r] - mnew);
            Mx[r] = mnew;
        }
        float rs[4] = {0.f, 0.f, 0.f, 0.f};
        for (int j = 0; j < 4; j++)
            for (int r = 0; r < 4; r++) {
                float p = __expf(sac[j][r] - Mx[r]);
                rs[r] += p;
                Pl[(fg * 4 + r) * 64 + j * 16 + fr] = f2bf(p);
            }
        for (int r = 0; r < 4; r++) {
            float tsum = rs[r];
            tsum += __shfl_xor(tsum, 1);
            tsum += __shfl_xor(tsum, 2);
            tsum += __shfl_xor(tsum, 4);
            tsum += __shfl_xor(tsum, 8);
            L[r] = L[r] * alpha[r] + tsum;
        }
        for (int jo = 0; jo < 8; jo++)
            for (int r = 0; r < 4; r++) o[jo][r] *= alpha[r];
        __syncthreads();
        s16x8 pa[2];
        for (int ks = 0; ks < 2; ks++)
            pa[ks] = *(const s16x8*)(Pl + fr * 64 + ks * 32 + fg * 8);
        for (int jo = 0; jo < 8; jo++) {
            const unsigned short* vp = vbase + (size_t)(jo * 16) * TT + tk0;
            for (int ks = 0; ks < 2; ks++) {
                s16x8 vf = *(const s16x8*)(vp + ks * 32);
                o[jo] = __builtin_amdgcn_mfma_f32_16x16x32_bf16(pa[ks], vf, o[jo], 0, 0, 0);
            }
        }
        __syncthreads();
    }
    float Linv[4];
    for (int r = 0; r < 4; r++) Linv[r] = 1.f / L[r];
    for (int jo = 0; jo < 8; jo++)
        for (int r = 0; r < 4; r++) {
            float val = o[jo][r] * Linv[r];
            Y[((size_t)(b * TT + q0 + fg * 4 + r)) * DD + h * HDD + jo * 16 + fr] = f2bf(val);
        }
}

// ---------------- launch ----------------
extern "C" void kernel_launch(void* const* d_in, const int* in_sizes, int n_in,
                              void* d_out, int out_size, void* d_ws, size_t ws_size,
                              hipStream_t stream) {
    const float* x = (const float*)d_in[0];
    auto F = [&](int i) { return (const float*)d_in[i]; };
    char* ws = (char*)d_ws;
    const size_t MB = 1ull << 20;

    // bf16 weights: 8 attn (8MB each) then 4 mlp (32MB each)
    static const int widx_[12] = {1, 3, 5, 7, 9, 11, 13, 15, 17, 19, 21, 23};
    static const size_t woffMB[12] = {0, 8, 16, 24, 32, 40, 48, 56, 64, 96, 128, 160};
    unsigned short* wbf[12];
    for (int i = 0; i < 12; i++) {
        wbf[i] = (unsigned short*)(ws + woffMB[i] * MB);
        size_t n = (i < 8) ? (size_t)DD * DD : (size_t)4 * DD * DD;
        cvt_bf16<<<dim3((unsigned)(n / 4 / 256)), dim3(256), 0, stream>>>(F(widx_[i]), wbf[i], (int)(n / 4));
    }
    unsigned short* hbf = (unsigned short*)(ws + 192 * MB);  // 16MB (ln1 out, reused ln2 out)
    unsigned short* qb  = (unsigned short*)(ws + 208 * MB);  // 16MB
    unsigned short* kb  = (unsigned short*)(ws + 224 * MB);  // 16MB
    unsigned short* vtb = (unsigned short*)(ws + 240 * MB);  // 16MB (transposed V)
    unsigned short* yb  = (unsigned short*)(ws + 256 * MB);  // 16MB
    unsigned short* ub  = (unsigned short*)(ws + 208 * MB);  // 64MB, overlaps q/k/vT/y (dead by then)
    float* x1 = (float*)(ws + 272 * MB);                     // 32MB fp32

    ln_bf16<<<dim3(MROWS), dim3(256), 0, stream>>>(x, F(25), F(26), hbf);

    dim3 blk(256);
    gemm_gated<0><<<dim3(16, 32), blk, 0, stream>>>(hbf, wbf[0], wbf[1], F(2), F(4), nullptr, qb, MROWS, DD, DD);
    gemm_gated<0><<<dim3(16, 32), blk, 0, stream>>>(hbf, wbf[2], wbf[3], F(6), F(8), nullptr, kb, MROWS, DD, DD);
    gemm_gated<1><<<dim3(16, 32), blk, 0, stream>>>(hbf, wbf[4], wbf[5], F(10), F(12), nullptr, vtb, MROWS, DD, DD);

    attn_flash<<<dim3(4096), dim3(64), 0, stream>>>(qb, kb, vtb, yb);

    gemm_gated<2><<<dim3(16, 32), blk, 0, stream>>>(yb, wbf[6], wbf[7], F(14), F(16), x, x1, MROWS, DD, DD);

    ln_bf16<<<dim3(MROWS), dim3(256), 0, stream>>>(x1, F(27), F(28), hbf);

    gemm_gated<3><<<dim3(64, 32), blk, 0, stream>>>(hbf, wbf[8], wbf[9], F(18), F(20), nullptr, ub, MROWS, 4 * DD, DD);
    gemm_gated<2><<<dim3(16, 32), blk, 0, stream>>>(ub, wbf[10], wbf[11], F(22), F(24), x1, (float*)d_out, MROWS, DD, 4 * DD);
}

// Round 2
// 1940.810 us; speedup vs baseline: 2.3225x; 2.3225x over previous
//
#include <hip/hip_runtime.h>
#include <cstdint>
#include <cmath>

#define DD 2048
#define TT 2048
#define HH 16
#define HDD 128
#define MROWS 4096  // B*T

typedef __attribute__((ext_vector_type(8))) short s16x8;
typedef __attribute__((ext_vector_type(4))) float f32x4;

typedef const __attribute__((address_space(1))) void gvoid;
typedef __attribute__((address_space(3))) void lvoid;

__device__ __forceinline__ void async_cp16(const void* g, void* l) {
    __builtin_amdgcn_global_load_lds((gvoid*)g, (lvoid*)l, 16, 0, 0);
}

__device__ __forceinline__ unsigned short f2bf(float f) {
    unsigned int u = __float_as_uint(f);
    u += 0x7fffu + ((u >> 16) & 1u);
    return (unsigned short)(u >> 16);
}

__device__ __forceinline__ void store4bf(unsigned short* p, float a, float b, float c, float d) {
    union { unsigned short u[4]; uint2 v; } x;
    x.u[0] = f2bf(a); x.u[1] = f2bf(b); x.u[2] = f2bf(c); x.u[3] = f2bf(d);
    *(uint2*)p = x.v;
}

// ---------------- fp32 -> bf16 convert ----------------
__global__ __launch_bounds__(256) void cvt_bf16(const float* __restrict__ src,
                                                unsigned short* __restrict__ dst, int n4) {
    int i = blockIdx.x * 256 + threadIdx.x;
    if (i < n4) {
        float4 v = ((const float4*)src)[i];
        store4bf(dst + (size_t)i * 4, v.x, v.y, v.z, v.w);
    }
}

// ---------------- LayerNorm (fp32 in, bf16 out) ----------------
__global__ __launch_bounds__(256) void ln_bf16(const float* __restrict__ x,
                                               const float* __restrict__ gg,
                                               const float* __restrict__ bb,
                                               unsigned short* __restrict__ out) {
    __shared__ float red[8];
    const int row = blockIdx.x, t = threadIdx.x;
    const float* xr = x + (size_t)row * DD;
    float4 a = ((const float4*)xr)[t];
    float4 c = ((const float4*)xr)[t + 256];
    float s = a.x + a.y + a.z + a.w + c.x + c.y + c.z + c.w;
    float q = a.x*a.x + a.y*a.y + a.z*a.z + a.w*a.w + c.x*c.x + c.y*c.y + c.z*c.z + c.w*c.w;
    #pragma unroll
    for (int m = 1; m < 64; m <<= 1) { s += __shfl_xor(s, m); q += __shfl_xor(q, m); }
    if ((t & 63) == 0) { red[t >> 6] = s; red[4 + (t >> 6)] = q; }
    __syncthreads();
    s = red[0] + red[1] + red[2] + red[3];
    q = red[4] + red[5] + red[6] + red[7];
    float mean = s * (1.f / DD);
    float var = q * (1.f / DD) - mean * mean;
    float rstd = rsqrtf(var + 1e-5f);
    float4 g1 = ((const float4*)gg)[t], b1 = ((const float4*)bb)[t];
    float4 g2 = ((const float4*)gg)[t + 256], b2 = ((const float4*)bb)[t + 256];
    unsigned short* orow = out + (size_t)row * DD;
    store4bf(orow + 4 * t,
             (a.x - mean) * rstd * g1.x + b1.x, (a.y - mean) * rstd * g1.y + b1.y,
             (a.z - mean) * rstd * g1.z + b1.z, (a.w - mean) * rstd * g1.w + b1.w);
    store4bf(orow + 1024 + 4 * t,
             (c.x - mean) * rstd * g2.x + b2.x, (c.y - mean) * rstd * g2.y + b2.y,
             (c.z - mean) * rstd * g2.z + b2.z, (c.w - mean) * rstd * g2.w + b2.w);
}

// ---------------- dual gated GEMM ----------------
// out[m,n] = epi( (A·W^T + b)[m,n] * sigmoid((A·Wg^T + bg)[m,n]) )
// A: MxK bf16 row-major; W,Wg: NxK bf16 row-major. Tile 128m x 64n, BK=32.
// 4 waves in 2(m) x 2(n); per wave 64x32 dual acc = 64 VGPRs of accumulator.
// EPI: 0 = bf16 store (q,k); 1 = bf16 transposed-V store via LDS; 2 = fp32 resid add; 3 = gelu->bf16
template <int EPI>
__global__ __launch_bounds__(256, 3) void gemm_gated(
        const unsigned short* __restrict__ A, const unsigned short* __restrict__ W,
        const unsigned short* __restrict__ Wg, const float* __restrict__ bias,
        const float* __restrict__ biasg, const float* __restrict__ resid,
        void* __restrict__ outp, int M, int N, int K) {
    // staging (ushort idx): A[128][32] @0..4096, B[64][32] @4096..6144, Bg @6144..8192
    // EPI==1 additionally needs a 64x136 transpose buffer (8704 ushorts), reusing same LDS.
    __shared__ unsigned short lds_[(EPI == 1) ? 8704 : 8192];
    const int t = threadIdx.x, lane = t & 63, wv = t >> 6;
    const int m0 = blockIdx.y * 128, n0 = blockIdx.x * 64;

    const int srow = t >> 2;             // 0..63
    const int scol = (t & 3) * 8;        // 0/8/16/24
    const unsigned short* gA = A + (size_t)(m0 + srow) * K + scol;
    const unsigned short* gB = W + (size_t)(n0 + srow) * K + scol;
    const unsigned short* gBg = Wg + (size_t)(n0 + srow) * K + scol;

    const int mw = (wv >> 1) * 64, nw = (wv & 1) * 32;
    const int fr = lane & 15, fg = lane >> 4, fk = fg * 8;

    f32x4 zero4 = {0.f, 0.f, 0.f, 0.f};
    f32x4 acc[4][2], accg[4][2];
    #pragma unroll
    for (int i = 0; i < 4; i++)
        #pragma unroll
        for (int j = 0; j < 2; j++) { acc[i][j] = zero4; accg[i][j] = zero4; }

    for (int k0 = 0; k0 < K; k0 += 32) {
        async_cp16(gA + k0, lds_ + t * 8);                          // A rows 0..63
        async_cp16(gA + (size_t)64 * K + k0, lds_ + 2048 + t * 8);  // A rows 64..127
        async_cp16(gB + k0, lds_ + 4096 + t * 8);                   // B rows 0..63
        async_cp16(gBg + k0, lds_ + 6144 + t * 8);                  // Bg rows 0..63
        __syncthreads();
        s16x8 af[4], bf_[2], bg_[2];
        #pragma unroll
        for (int i = 0; i < 4; i++)
            af[i] = *(const s16x8*)(lds_ + (mw + i * 16 + fr) * 32 + fk);
        #pragma unroll
        for (int j = 0; j < 2; j++) {
            bf_[j] = *(const s16x8*)(lds_ + 4096 + (nw + j * 16 + fr) * 32 + fk);
            bg_[j] = *(const s16x8*)(lds_ + 6144 + (nw + j * 16 + fr) * 32 + fk);
        }
        #pragma unroll
        for (int i = 0; i < 4; i++)
            #pragma unroll
            for (int j = 0; j < 2; j++) {
                acc[i][j] = __builtin_amdgcn_mfma_f32_16x16x32_bf16(af[i], bf_[j], acc[i][j], 0, 0, 0);
                accg[i][j] = __builtin_amdgcn_mfma_f32_16x16x32_bf16(af[i], bg_[j], accg[i][j], 0, 0, 0);
            }
        __syncthreads();
    }

    #pragma unroll
    for (int i = 0; i < 4; i++)
        #pragma unroll
        for (int j = 0; j < 2; j++) {
            const int n = n0 + nw + j * 16 + fr;
            const float bn = bias[n], bgn = biasg[n];
            #pragma unroll
            for (int r = 0; r < 4; r++) {
                const int m = m0 + mw + i * 16 + fg * 4 + r;
                float lin = acc[i][j][r] + bn;
                float gt = accg[i][j][r] + bgn;
                float gv = lin / (1.f + __expf(-gt));
                if constexpr (EPI == 0) {
                    ((unsigned short*)outp)[(size_t)m * N + n] = f2bf(gv);
                } else if constexpr (EPI == 1) {
                    // stash into LDS transpose buffer [n_local][m_local], stride 136
                    lds_[(nw + j * 16 + fr) * 136 + (mw + i * 16 + fg * 4 + r)] = f2bf(gv);
                } else if constexpr (EPI == 2) {
                    ((float*)outp)[(size_t)m * N + n] = resid[(size_t)m * N + n] + gv;
                } else {
                    float ge = 0.5f * gv * (1.f + erff(gv * 0.70710678118f));
                    ((unsigned short*)outp)[(size_t)m * N + n] = f2bf(ge);
                }
            }
        }

    if constexpr (EPI == 1) {
        __syncthreads();
        // coalesced write-out: vT[((b*H + h)*HD + hd)*T + t_seq]
        const int n_l = t >> 2;       // 0..63  (hd within this tile)
        const int ch = t & 3;         // 32-elem chunk of the 128 m values
        const unsigned short* src = lds_ + n_l * 136 + ch * 32;
        const int hglob = n0 + n_l;           // 0..2047
        const int b_ = m0 >> 11;
        const int tseq = (m0 & 2047) + ch * 32;
        unsigned short* dst = (unsigned short*)outp +
            (((size_t)b_ * HH + (hglob >> 7)) * HDD + (hglob & 127)) * TT + tseq;
        #pragma unroll
        for (int c = 0; c < 4; c++)
            *(uint4*)(dst + c * 8) = *(const uint4*)(src + c * 8);
    }
}

// ---------------- flash attention ----------------
// One wave (64 thr) per (b, h, 16 q-rows). Q,K normal layout [ (b*T+t)*D + h*HD+hd ],
// V transposed [ ((b*H+h)*HD+hd)*T + t ]. Full softmax (no mask).
__global__ __launch_bounds__(64) void attn_flash(const unsigned short* __restrict__ Q,
                                                 const unsigned short* __restrict__ Kb,
                                                 const unsigned short* __restrict__ VT,
                                                 unsigned short* __restrict__ Y) {
    __shared__ unsigned short Pl[16 * 64];
    const int lane = threadIdx.x;
    const int bx = blockIdx.x;
    const int q0 = (bx & 127) * 16;
    const int h = (bx >> 7) & 15;
    const int b = bx >> 11;
    const int fr = lane & 15, fg = lane >> 4;

    s16x8 qf[4];
    const unsigned short* qbase = Q + ((size_t)(b * TT + q0 + fr)) * DD + h * HDD + fg * 8;
    #pragma unroll
    for (int s = 0; s < 4; s++) qf[s] = *(const s16x8*)(qbase + s * 32);

    f32x4 zero4 = {0.f, 0.f, 0.f, 0.f};
    f32x4 o[8];
    #pragma unroll
    for (int jo = 0; jo < 8; jo++) o[jo] = zero4;
    float Mx[4], L[4];
    #pragma unroll
    for (int r = 0; r < 4; r++) { Mx[r] = -1e30f; L[r] = 0.f; }

    const unsigned short* kbase = Kb + (size_t)(b * TT) * DD + h * HDD + fg * 8;
    const unsigned short* vbase = VT + ((size_t)((b * HH + h) * HDD + fr)) * TT + fg * 8;
    const float scale = 0.08838834764831845f;  // 1/sqrt(128)

    for (int tk0 = 0; tk0 < TT; tk0 += 64) {
        f32x4 sac[4];
        #pragma unroll
        for (int j = 0; j < 4; j++) sac[j] = zero4;
        #pragma unroll
        for (int j = 0; j < 4; j++) {
            const unsigned short* kp = kbase + (size_t)(tk0 + j * 16 + fr) * DD;
            #pragma unroll
            for (int s = 0; s < 4; s++) {
                s16x8 kf = *(const s16x8*)(kp + s * 32);
                sac[j] = __builtin_amdgcn_mfma_f32_16x16x32_bf16(qf[s], kf, sac[j], 0, 0, 0);
            }
        }
        float alpha[4];
        #pragma unroll
        for (int j = 0; j < 4; j++)
            #pragma unroll
            for (int r = 0; r < 4; r++) sac[j][r] *= scale;
        #pragma unroll
        for (int r = 0; r < 4; r++) {
            float mx = fmaxf(fmaxf(sac[0][r], sac[1][r]), fmaxf(sac[2][r], sac[3][r]));
            mx = fmaxf(mx, __shfl_xor(mx, 1));
            mx = fmaxf(mx, __shfl_xor(mx, 2));
            mx = fmaxf(mx, __shfl_xor(mx, 4));
            mx = fmaxf(mx, __shfl_xor(mx, 8));
            float mnew = fmaxf(Mx[r], mx);
            alpha[r] = __expf(Mx[r] - mnew);
            Mx[r] = mnew;
        }
        float rs[4] = {0.f, 0.f, 0.f, 0.f};
        #pragma unroll
        for (int j = 0; j < 4; j++)
            #pragma unroll
            for (int r = 0; r < 4; r++) {
                float p = __expf(sac[j][r] - Mx[r]);
                rs[r] += p;
                Pl[(fg * 4 + r) * 64 + j * 16 + fr] = f2bf(p);
            }
        #pragma unroll
        for (int r = 0; r < 4; r++) {
            float tsum = rs[r];
            tsum += __shfl_xor(tsum, 1);
            tsum += __shfl_xor(tsum, 2);
            tsum += __shfl_xor(tsum, 4);
            tsum += __shfl_xor(tsum, 8);
            L[r] = L[r] * alpha[r] + tsum;
        }
        #pragma unroll
        for (int jo = 0; jo < 8; jo++)
            #pragma unroll
            for (int r = 0; r < 4; r++) o[jo][r] *= alpha[r];
        __syncthreads();
        s16x8 pa[2];
        #pragma unroll
        for (int ks = 0; ks < 2; ks++)
            pa[ks] = *(const s16x8*)(Pl + fr * 64 + ks * 32 + fg * 8);
        #pragma unroll
        for (int jo = 0; jo < 8; jo++) {
            const unsigned short* vp = vbase + (size_t)(jo * 16) * TT + tk0;
            #pragma unroll
            for (int ks = 0; ks < 2; ks++) {
                s16x8 vf = *(const s16x8*)(vp + ks * 32);
                o[jo] = __builtin_amdgcn_mfma_f32_16x16x32_bf16(pa[ks], vf, o[jo], 0, 0, 0);
            }
        }
        __syncthreads();
    }
    float Linv[4];
    #pragma unroll
    for (int r = 0; r < 4; r++) Linv[r] = 1.f / L[r];
    #pragma unroll
    for (int jo = 0; jo < 8; jo++)
        #pragma unroll
        for (int r = 0; r < 4; r++) {
            float val = o[jo][r] * Linv[r];
            Y[((size_t)(b * TT + q0 + fg * 4 + r)) * DD + h * HDD + jo * 16 + fr] = f2bf(val);
        }
}

// ---------------- launch ----------------
extern "C" void kernel_launch(void* const* d_in, const int* in_sizes, int n_in,
                              void* d_out, int out_size, void* d_ws, size_t ws_size,
                              hipStream_t stream) {
    const float* x = (const float*)d_in[0];
    auto F = [&](int i) { return (const float*)d_in[i]; };
    char* ws = (char*)d_ws;
    const size_t MB = 1ull << 20;

    // bf16 weights: 8 attn (8MB each) then 4 mlp (32MB each)
    static const int widx_[12] = {1, 3, 5, 7, 9, 11, 13, 15, 17, 19, 21, 23};
    static const size_t woffMB[12] = {0, 8, 16, 24, 32, 40, 48, 56, 64, 96, 128, 160};
    unsigned short* wbf[12];
    for (int i = 0; i < 12; i++) {
        wbf[i] = (unsigned short*)(ws + woffMB[i] * MB);
        size_t n = (i < 8) ? (size_t)DD * DD : (size_t)4 * DD * DD;
        cvt_bf16<<<dim3((unsigned)(n / 4 / 256)), dim3(256), 0, stream>>>(F(widx_[i]), wbf[i], (int)(n / 4));
    }
    unsigned short* hbf = (unsigned short*)(ws + 192 * MB);  // 16MB (ln1 out, reused ln2 out)
    unsigned short* qb  = (unsigned short*)(ws + 208 * MB);  // 16MB
    unsigned short* kb  = (unsigned short*)(ws + 224 * MB);  // 16MB
    unsigned short* vtb = (unsigned short*)(ws + 240 * MB);  // 16MB (transposed V)
    unsigned short* yb  = (unsigned short*)(ws + 256 * MB);  // 16MB
    unsigned short* ub  = (unsigned short*)(ws + 208 * MB);  // 64MB, overlaps q/k/vT/y (dead by then)
    float* x1 = (float*)(ws + 272 * MB);                     // 32MB fp32

    ln_bf16<<<dim3(MROWS), dim3(256), 0, stream>>>(x, F(25), F(26), hbf);

    dim3 blk(256);
    gemm_gated<0><<<dim3(32, 32), blk, 0, stream>>>(hbf, wbf[0], wbf[1], F(2), F(4), nullptr, qb, MROWS, DD, DD);
    gemm_gated<0><<<dim3(32, 32), blk, 0, stream>>>(hbf, wbf[2], wbf[3], F(6), F(8), nullptr, kb, MROWS, DD, DD);
    gemm_gated<1><<<dim3(32, 32), blk, 0, stream>>>(hbf, wbf[4], wbf[5], F(10), F(12), nullptr, vtb, MROWS, DD, DD);

    attn_flash<<<dim3(4096), dim3(64), 0, stream>>>(qb, kb, vtb, yb);

    gemm_gated<2><<<dim3(32, 32), blk, 0, stream>>>(yb, wbf[6], wbf[7], F(14), F(16), x, x1, MROWS, DD, DD);

    ln_bf16<<<dim3(MROWS), dim3(256), 0, stream>>>(x1, F(27), F(28), hbf);

    gemm_gated<3><<<dim3(128, 32), blk, 0, stream>>>(hbf, wbf[8], wbf[9], F(18), F(20), nullptr, ub, MROWS, 4 * DD, DD);
    gemm_gated<2><<<dim3(32, 32), blk, 0, stream>>>(ub, wbf[10], wbf[11], F(22), F(24), x1, (float*)d_out, MROWS, DD, 4 * DD);
}

// Round 3
// 1708.768 us; speedup vs baseline: 2.6379x; 1.1358x over previous
//
#include <hip/hip_runtime.h>
#include <cstdint>
#include <cmath>

#define DD 2048
#define TT 2048
#define HH 16
#define HDD 128
#define MROWS 4096  // B*T

typedef __attribute__((ext_vector_type(8))) short s16x8;
typedef __attribute__((ext_vector_type(4))) float f32x4;

typedef const __attribute__((address_space(1))) void gvoid;
typedef __attribute__((address_space(3))) void lvoid;

__device__ __forceinline__ void async_cp16(const void* g, void* l) {
    __builtin_amdgcn_global_load_lds((gvoid*)g, (lvoid*)l, 16, 0, 0);
}

__device__ __forceinline__ unsigned short f2bf(float f) {
    unsigned int u = __float_as_uint(f);
    u += 0x7fffu + ((u >> 16) & 1u);
    return (unsigned short)(u >> 16);
}

__device__ __forceinline__ void store4bf(unsigned short* p, float a, float b, float c, float d) {
    union { unsigned short u[4]; uint2 v; } x;
    x.u[0] = f2bf(a); x.u[1] = f2bf(b); x.u[2] = f2bf(c); x.u[3] = f2bf(d);
    *(uint2*)p = x.v;
}

// ---------------- fp32 -> bf16 convert ----------------
__global__ __launch_bounds__(256) void cvt_bf16(const float* __restrict__ src,
                                                unsigned short* __restrict__ dst, int n4) {
    int i = blockIdx.x * 256 + threadIdx.x;
    if (i < n4) {
        float4 v = ((const float4*)src)[i];
        store4bf(dst + (size_t)i * 4, v.x, v.y, v.z, v.w);
    }
}

// ---------------- LayerNorm (fp32 in, bf16 out) ----------------
__global__ __launch_bounds__(256) void ln_bf16(const float* __restrict__ x,
                                               const float* __restrict__ gg,
                                               const float* __restrict__ bb,
                                               unsigned short* __restrict__ out) {
    __shared__ float red[8];
    const int row = blockIdx.x, t = threadIdx.x;
    const float* xr = x + (size_t)row * DD;
    float4 a = ((const float4*)xr)[t];
    float4 c = ((const float4*)xr)[t + 256];
    float s = a.x + a.y + a.z + a.w + c.x + c.y + c.z + c.w;
    float q = a.x*a.x + a.y*a.y + a.z*a.z + a.w*a.w + c.x*c.x + c.y*c.y + c.z*c.z + c.w*c.w;
    #pragma unroll
    for (int m = 1; m < 64; m <<= 1) { s += __shfl_xor(s, m); q += __shfl_xor(q, m); }
    if ((t & 63) == 0) { red[t >> 6] = s; red[4 + (t >> 6)] = q; }
    __syncthreads();
    s = red[0] + red[1] + red[2] + red[3];
    q = red[4] + red[5] + red[6] + red[7];
    float mean = s * (1.f / DD);
    float var = q * (1.f / DD) - mean * mean;
    float rstd = rsqrtf(var + 1e-5f);
    float4 g1 = ((const float4*)gg)[t], b1 = ((const float4*)bb)[t];
    float4 g2 = ((const float4*)gg)[t + 256], b2 = ((const float4*)bb)[t + 256];
    unsigned short* orow = out + (size_t)row * DD;
    store4bf(orow + 4 * t,
             (a.x - mean) * rstd * g1.x + b1.x, (a.y - mean) * rstd * g1.y + b1.y,
             (a.z - mean) * rstd * g1.z + b1.z, (a.w - mean) * rstd * g1.w + b1.w);
    store4bf(orow + 1024 + 4 * t,
             (c.x - mean) * rstd * g2.x + b2.x, (c.y - mean) * rstd * g2.y + b2.y,
             (c.z - mean) * rstd * g2.z + b2.z, (c.w - mean) * rstd * g2.w + b2.w);
}

// ---------------- dual gated GEMM ----------------
// out[m,n] = epi( (A·W^T + b)[m,n] * sigmoid((A·Wg^T + bg)[m,n]) )
// Tile 128m x 64n, BK=32; 4 waves 2x2; supergroup swizzle GM=8 for L2 locality.
// EPI: 0 = bf16 store; 1 = bf16 transposed-V store via LDS; 2 = fp32 resid add; 3 = gelu->bf16
template <int EPI>
__global__ __launch_bounds__(256, 3) void gemm_gated(
        const unsigned short* __restrict__ A, const unsigned short* __restrict__ W,
        const unsigned short* __restrict__ Wg, const float* __restrict__ bias,
        const float* __restrict__ biasg, const float* __restrict__ resid,
        void* __restrict__ outp, int M, int N, int K) {
    __shared__ unsigned short lds_[(EPI == 1) ? 8704 : 8192];
    const int t = threadIdx.x, lane = t & 63, wv = t >> 6;

    // supergroup swizzle: 8 consecutive blocks share a B-tile; block i of the
    // group lands on XCD i (round-robin dispatch), pinning its A-tile in that XCD's L2.
    const int nbg = gridDim.x;
    int pid = blockIdx.y * nbg + blockIdx.x;
    int npg = 8 * nbg;
    int grp = pid / npg;
    int loc = pid - grp * npg;
    const int m0 = (grp * 8 + (loc & 7)) * 128;
    const int n0 = (loc >> 3) * 64;

    const int srow = t >> 2;             // 0..63
    const int scol = (t & 3) * 8;        // 0/8/16/24
    const unsigned short* gA = A + (size_t)(m0 + srow) * K + scol;
    const unsigned short* gB = W + (size_t)(n0 + srow) * K + scol;
    const unsigned short* gBg = Wg + (size_t)(n0 + srow) * K + scol;

    const int mw = (wv >> 1) * 64, nw = (wv & 1) * 32;
    const int fr = lane & 15, fg = lane >> 4, fk = fg * 8;

    f32x4 zero4 = {0.f, 0.f, 0.f, 0.f};
    f32x4 acc[4][2], accg[4][2];
    #pragma unroll
    for (int i = 0; i < 4; i++)
        #pragma unroll
        for (int j = 0; j < 2; j++) { acc[i][j] = zero4; accg[i][j] = zero4; }

    for (int k0 = 0; k0 < K; k0 += 32) {
        async_cp16(gA + k0, lds_ + t * 8);
        async_cp16(gA + (size_t)64 * K + k0, lds_ + 2048 + t * 8);
        async_cp16(gB + k0, lds_ + 4096 + t * 8);
        async_cp16(gBg + k0, lds_ + 6144 + t * 8);
        __syncthreads();
        s16x8 af[4], bf_[2], bg_[2];
        #pragma unroll
        for (int i = 0; i < 4; i++)
            af[i] = *(const s16x8*)(lds_ + (mw + i * 16 + fr) * 32 + fk);
        #pragma unroll
        for (int j = 0; j < 2; j++) {
            bf_[j] = *(const s16x8*)(lds_ + 4096 + (nw + j * 16 + fr) * 32 + fk);
            bg_[j] = *(const s16x8*)(lds_ + 6144 + (nw + j * 16 + fr) * 32 + fk);
        }
        #pragma unroll
        for (int i = 0; i < 4; i++)
            #pragma unroll
            for (int j = 0; j < 2; j++) {
                acc[i][j] = __builtin_amdgcn_mfma_f32_16x16x32_bf16(af[i], bf_[j], acc[i][j], 0, 0, 0);
                accg[i][j] = __builtin_amdgcn_mfma_f32_16x16x32_bf16(af[i], bg_[j], accg[i][j], 0, 0, 0);
            }
        __syncthreads();
    }

    #pragma unroll
    for (int i = 0; i < 4; i++)
        #pragma unroll
        for (int j = 0; j < 2; j++) {
            const int n = n0 + nw + j * 16 + fr;
            const float bn = bias[n], bgn = biasg[n];
            #pragma unroll
            for (int r = 0; r < 4; r++) {
                const int m = m0 + mw + i * 16 + fg * 4 + r;
                float lin = acc[i][j][r] + bn;
                float gt = accg[i][j][r] + bgn;
                float gv = lin / (1.f + __expf(-gt));
                if constexpr (EPI == 0) {
                    ((unsigned short*)outp)[(size_t)m * N + n] = f2bf(gv);
                } else if constexpr (EPI == 1) {
                    lds_[(nw + j * 16 + fr) * 136 + (mw + i * 16 + fg * 4 + r)] = f2bf(gv);
                } else if constexpr (EPI == 2) {
                    ((float*)outp)[(size_t)m * N + n] = resid[(size_t)m * N + n] + gv;
                } else {
                    float ge = 0.5f * gv * (1.f + erff(gv * 0.70710678118f));
                    ((unsigned short*)outp)[(size_t)m * N + n] = f2bf(ge);
                }
            }
        }

    if constexpr (EPI == 1) {
        __syncthreads();
        // coalesced write-out: vT[((b*H + h)*HD + hd)*T + t_seq]
        const int n_l = t >> 2;
        const int ch = t & 3;
        const unsigned short* src = lds_ + n_l * 136 + ch * 32;
        const int hglob = n0 + n_l;
        const int b_ = m0 >> 11;
        const int tseq = (m0 & 2047) + ch * 32;
        unsigned short* dst = (unsigned short*)outp +
            (((size_t)b_ * HH + (hglob >> 7)) * HDD + (hglob & 127)) * TT + tseq;
        #pragma unroll
        for (int c = 0; c < 4; c++)
            *(uint4*)(dst + c * 8) = *(const uint4*)(src + c * 8);
    }
}

// ---------------- flash attention v2 ----------------
// 256 threads = 4 waves per block; block handles 64 q-rows; K/V tiles (64 keys)
// staged in LDS via global_load_lds with XOR-swizzled chunk layout (conflict-free reads).
// Q,K: [(b*T+t)*D + h*HD+hd]; V transposed: [((b*H+h)*HD+hd)*T + t].
__global__ __launch_bounds__(256, 4) void attn_flash2(const unsigned short* __restrict__ Q,
                                                      const unsigned short* __restrict__ Kb,
                                                      const unsigned short* __restrict__ VT,
                                                      unsigned short* __restrict__ Y) {
    __shared__ unsigned short sK[64 * 128];   // 16 KB, chunk c stored at c^(row&15)
    __shared__ unsigned short sV[128 * 64];   // 16 KB, chunk c stored at c^(row&7)
    __shared__ unsigned short sP[4 * 1024];   // 2 KB per wave, chunk c at c^(row&7)
    const int t = threadIdx.x, lane = t & 63, wv = t >> 6;
    const int bx = blockIdx.x;
    const int qblk = bx & 31;
    const int h = (bx >> 5) & 15;
    const int b = bx >> 9;
    const int q0 = qblk * 64 + wv * 16;
    const int fr = lane & 15, fg = lane >> 4;

    s16x8 qf[4];
    const unsigned short* qbase = Q + ((size_t)(b * TT + q0 + fr)) * DD + h * HDD + fg * 8;
    #pragma unroll
    for (int s = 0; s < 4; s++) qf[s] = *(const s16x8*)(qbase + s * 32);

    // staging source pointers (swizzled): K round r covers rows r*16+t/16, pos-chunk t&15
    const unsigned short* kSrc[4];
    const unsigned short* vSrc[4];
    #pragma unroll
    for (int r = 0; r < 4; r++) {
        int R = r * 16 + (t >> 4);
        int c = (t & 15) ^ ((t >> 4) & 15);
        kSrc[r] = Kb + (size_t)(b * TT + R) * DD + h * HDD + c * 8;
        int hd = r * 32 + (t >> 3);
        int cv = (t & 7) ^ ((t >> 3) & 7);
        vSrc[r] = VT + ((size_t)((b * HH + h) * HDD + hd)) * TT + cv * 8;
    }
    unsigned short* sPw = sP + wv * 1024;

    f32x4 zero4 = {0.f, 0.f, 0.f, 0.f};
    f32x4 o[8];
    #pragma unroll
    for (int jo = 0; jo < 8; jo++) o[jo] = zero4;
    float Mx[4], L[4];
    #pragma unroll
    for (int r = 0; r < 4; r++) { Mx[r] = -1e30f; L[r] = 0.f; }
    const float scale = 0.08838834764831845f;  // 1/sqrt(128)

    for (int tk0 = 0; tk0 < TT; tk0 += 64) {
        #pragma unroll
        for (int r = 0; r < 4; r++) {
            async_cp16(kSrc[r] + (size_t)tk0 * DD, sK + r * 2048 + t * 8);
            async_cp16(vSrc[r] + tk0, sV + r * 2048 + t * 8);
        }
        __syncthreads();

        // QK^T from LDS (swizzled reads, ~2-way max)
        f32x4 sac[4];
        #pragma unroll
        for (int j = 0; j < 4; j++) sac[j] = zero4;
        #pragma unroll
        for (int j = 0; j < 4; j++)
            #pragma unroll
            for (int s = 0; s < 4; s++) {
                s16x8 kf = *(const s16x8*)(sK + (j * 16 + fr) * 128 + (((s * 4 + fg) ^ fr) * 8));
                sac[j] = __builtin_amdgcn_mfma_f32_16x16x32_bf16(qf[s], kf, sac[j], 0, 0, 0);
            }

        float alpha[4];
        #pragma unroll
        for (int j = 0; j < 4; j++)
            #pragma unroll
            for (int r = 0; r < 4; r++) sac[j][r] *= scale;
        #pragma unroll
        for (int r = 0; r < 4; r++) {
            float mx = fmaxf(fmaxf(sac[0][r], sac[1][r]), fmaxf(sac[2][r], sac[3][r]));
            mx = fmaxf(mx, __shfl_xor(mx, 1));
            mx = fmaxf(mx, __shfl_xor(mx, 2));
            mx = fmaxf(mx, __shfl_xor(mx, 4));
            mx = fmaxf(mx, __shfl_xor(mx, 8));
            float mnew = fmaxf(Mx[r], mx);
            alpha[r] = __expf(Mx[r] - mnew);
            Mx[r] = mnew;
        }
        float rs[4] = {0.f, 0.f, 0.f, 0.f};
        #pragma unroll
        for (int j = 0; j < 4; j++)
            #pragma unroll
            for (int r = 0; r < 4; r++) {
                float p = __expf(sac[j][r] - Mx[r]);
                rs[r] += p;
                // row q_r = fg*4+r, col = j*16+fr -> chunk c = j*2+(fr>>3), swizzle by row&7
                int qr = fg * 4 + r;
                int cc = (j * 2 + (fr >> 3)) ^ (qr & 7);
                sPw[qr * 64 + cc * 8 + (fr & 7)] = f2bf(p);
            }
        #pragma unroll
        for (int r = 0; r < 4; r++) {
            float tsum = rs[r];
            tsum += __shfl_xor(tsum, 1);
            tsum += __shfl_xor(tsum, 2);
            tsum += __shfl_xor(tsum, 4);
            tsum += __shfl_xor(tsum, 8);
            L[r] = L[r] * alpha[r] + tsum;
        }
        #pragma unroll
        for (int jo = 0; jo < 8; jo++)
            #pragma unroll
            for (int r = 0; r < 4; r++) o[jo][r] *= alpha[r];

        // P (per-wave, no barrier needed) + PV from LDS V
        s16x8 pa[2];
        #pragma unroll
        for (int ks = 0; ks < 2; ks++)
            pa[ks] = *(const s16x8*)(sPw + fr * 64 + (((ks * 4 + fg) ^ (fr & 7)) * 8));
        #pragma unroll
        for (int jo = 0; jo < 8; jo++)
            #pragma unroll
            for (int ks = 0; ks < 2; ks++) {
                s16x8 vf = *(const s16x8*)(sV + (jo * 16 + fr) * 64 + (((ks * 4 + fg) ^ (fr & 7)) * 8));
                o[jo] = __builtin_amdgcn_mfma_f32_16x16x32_bf16(pa[ks], vf, o[jo], 0, 0, 0);
            }
        __syncthreads();
    }
    float Linv[4];
    #pragma unroll
    for (int r = 0; r < 4; r++) Linv[r] = 1.f / L[r];
    #pragma unroll
    for (int jo = 0; jo < 8; jo++)
        #pragma unroll
        for (int r = 0; r < 4; r++) {
            float val = o[jo][r] * Linv[r];
            Y[((size_t)(b * TT + q0 + fg * 4 + r)) * DD + h * HDD + jo * 16 + fr] = f2bf(val);
        }
}

// ---------------- launch ----------------
extern "C" void kernel_launch(void* const* d_in, const int* in_sizes, int n_in,
                              void* d_out, int out_size, void* d_ws, size_t ws_size,
                              hipStream_t stream) {
    const float* x = (const float*)d_in[0];
    auto F = [&](int i) { return (const float*)d_in[i]; };
    char* ws = (char*)d_ws;
    const size_t MB = 1ull << 20;

    static const int widx_[12] = {1, 3, 5, 7, 9, 11, 13, 15, 17, 19, 21, 23};
    static const size_t woffMB[12] = {0, 8, 16, 24, 32, 40, 48, 56, 64, 96, 128, 160};
    unsigned short* wbf[12];
    for (int i = 0; i < 12; i++) {
        wbf[i] = (unsigned short*)(ws + woffMB[i] * MB);
        size_t n = (i < 8) ? (size_t)DD * DD : (size_t)4 * DD * DD;
        cvt_bf16<<<dim3((unsigned)(n / 4 / 256)), dim3(256), 0, stream>>>(F(widx_[i]), wbf[i], (int)(n / 4));
    }
    unsigned short* hbf = (unsigned short*)(ws + 192 * MB);
    unsigned short* qb  = (unsigned short*)(ws + 208 * MB);
    unsigned short* kb  = (unsigned short*)(ws + 224 * MB);
    unsigned short* vtb = (unsigned short*)(ws + 240 * MB);
    unsigned short* yb  = (unsigned short*)(ws + 256 * MB);
    unsigned short* ub  = (unsigned short*)(ws + 208 * MB);  // overlaps q/k/vT/y (dead by then)
    float* x1 = (float*)(ws + 272 * MB);

    ln_bf16<<<dim3(MROWS), dim3(256), 0, stream>>>(x, F(25), F(26), hbf);

    dim3 blk(256);
    gemm_gated<0><<<dim3(32, 32), blk, 0, stream>>>(hbf, wbf[0], wbf[1], F(2), F(4), nullptr, qb, MROWS, DD, DD);
    gemm_gated<0><<<dim3(32, 32), blk, 0, stream>>>(hbf, wbf[2], wbf[3], F(6), F(8), nullptr, kb, MROWS, DD, DD);
    gemm_gated<1><<<dim3(32, 32), blk, 0, stream>>>(hbf, wbf[4], wbf[5], F(10), F(12), nullptr, vtb, MROWS, DD, DD);

    attn_flash2<<<dim3(1024), blk, 0, stream>>>(qb, kb, vtb, yb);

    gemm_gated<2><<<dim3(32, 32), blk, 0, stream>>>(yb, wbf[6], wbf[7], F(14), F(16), x, x1, MROWS, DD, DD);

    ln_bf16<<<dim3(MROWS), dim3(256), 0, stream>>>(x1, F(27), F(28), hbf);

    gemm_gated<3><<<dim3(128, 32), blk, 0, stream>>>(hbf, wbf[8], wbf[9], F(18), F(20), nullptr, ub, MROWS, 4 * DD, DD);
    gemm_gated<2><<<dim3(32, 32), blk, 0, stream>>>(ub, wbf[10], wbf[11], F(22), F(24), x1, (float*)d_out, MROWS, DD, 4 * DD);
}